// Round 7
// baseline (202.033 us; speedup 1.0000x reference)
//
#include <hip/hip_runtime.h>

#define S_DIM 512
#define B_DIM 16384
#define A_DIM 2
#define BA (B_DIM * A_DIM)   // 32768
#define HID 16
#define EMB 8
#define NPART 1000
#define TABN (NPART * HID)   // 16000
#define NG (S_DIM / 2)       // 256 groups of 2 steps

// Kernel 1: emb_proj[p][j] = b1[j] + sum_k emb_table[p][k] * W1[2+k][j]
__global__ __launch_bounds__(256) void emb_proj_kernel(
    const float* __restrict__ emb_table, const float* __restrict__ W1,
    const float* __restrict__ b1, float* __restrict__ proj) {
  int idx = blockIdx.x * 256 + threadIdx.x;
  if (idx >= TABN) return;
  int p = idx >> 4;
  int j = idx & 15;
  float acc = b1[j];
#pragma unroll
  for (int k = 0; k < EMB; ++k)
    acc = fmaf(emb_table[p * EMB + k], W1[(2 + k) * HID + j], acc);
  proj[idx] = acc;
}

// DPP quad-perm (pure VALU). 0xA0=[0,0,2,2] bcast even lane of pair,
// 0xF5=[1,1,3,3] bcast odd lane, 0xB1=[1,0,3,2] pair swap.
template <int CTRL>
__device__ __forceinline__ int dppi(int x) {
  return __builtin_amdgcn_update_dpp(0, x, CTRL, 0xF, 0xF, true);
}
template <int CTRL>
__device__ __forceinline__ float dppf(float x) {
  return __builtin_bit_cast(float, dppi<CTRL>(__builtin_bit_cast(int, x)));
}

// Scan: 2 lanes/chain, 8 hidden units/lane. 65536 threads = 1024 waves =
// 1 wave/SIMD, but issue-bound (dep path < issue). Groups of 2 steps;
// raw streams 2 groups ahead, table gather 1 group ahead. Pade[5/4] tanh
// with ONE batched rcp for all 8 units; Pade sigmoid. No DS ops at all.
__global__ __launch_bounds__(256, 1) void scan_kernel(
    const int* __restrict__ act, const float* __restrict__ rew,
    const int* __restrict__ pid, const float* __restrict__ W1,
    const float* __restrict__ W2, const float* __restrict__ b2,
    const float* __restrict__ proj, float* __restrict__ out) {
  int t = blockIdx.x * 256 + threadIdx.x;  // 0 .. 65535
  int chain = t >> 1;                      // 0 .. 32767 (= b*A + a)
  int sub = t & 1;                         // half of HID=16
  int b = chain >> 1;
  int j0 = sub << 3;                       // 8 units per lane

  float wa[8], wb[8], w2[8];
#pragma unroll
  for (int j = 0; j < 8; ++j) {
    wa[j] = W1[j0 + j];            // W1[0][j]
    wb[j] = W1[HID + j0 + j];      // W1[1][j]
    w2[j] = W2[j0 + j];            // W2[j][0]
  }
  float bb2 = b2[0];

  const float* rp = rew + chain;
  const int* ap = act + chain;
  const int* pp = pid + b;
  const float* tb = proj + j0;
  float* op = out + chain;

// lane sub covers step 2*G_+sub: one load per stream per 2-step group
#define LOAD_RAW(G_, RD, AD, PD)              \
  {                                           \
    int gg_ = (G_) < NG ? (G_) : NG - 1;      \
    size_t st_ = (size_t)(gg_ * 2 + sub);     \
    RD = rp[st_ * BA];                        \
    AD = ap[st_ * BA];                        \
    PD = pp[st_ * B_DIM];                     \
  }

// broadcast both steps' pids within the pair, fetch this lane's 8 columns
#define GATHER(PS, T0_, T1_)                                   \
  {                                                            \
    int pe_ = dppi<0xA0>(PS);                                  \
    int po_ = dppi<0xF5>(PS);                                  \
    float4 ga_ = *(const float4*)(tb + pe_ * HID);             \
    float4 gb_ = *(const float4*)(tb + pe_ * HID + 4);         \
    float4 gc_ = *(const float4*)(tb + po_ * HID);             \
    float4 gd_ = *(const float4*)(tb + po_ * HID + 4);         \
    T0_[0] = ga_.x; T0_[1] = ga_.y; T0_[2] = ga_.z; T0_[3] = ga_.w; \
    T0_[4] = gb_.x; T0_[5] = gb_.y; T0_[6] = gb_.z; T0_[7] = gb_.w; \
    T1_[0] = gc_.x; T1_[1] = gc_.y; T1_[2] = gc_.z; T1_[3] = gc_.w; \
    T1_[4] = gd_.x; T1_[5] = gd_.y; T1_[6] = gd_.z; T1_[7] = gd_.w; \
  }

// One step. PRE_[j] = r*wb[j] + emb_proj already folded in.
// tanh(x) (x in [0,4.6]) via Pade[5/4]; all 8 divisions share ONE rcp.
#define STEP(PRE_, AB_)                                               \
  {                                                                   \
    float n_[8], d_[8];                                               \
    _Pragma("unroll") for (int j = 0; j < 8; ++j) {                   \
      float xx = fmaf(state, wa[j], PRE_[j]);                         \
      xx = fminf(fmaxf(xx, 0.f), 4.6f);                               \
      float yy = xx * xx;                                             \
      n_[j] = xx * fmaf(yy, yy + 105.f, 945.f);                       \
      d_[j] = fmaf(yy, fmaf(yy, 15.f, 420.f), 945.f);                 \
    }                                                                 \
    float p01 = d_[0] * d_[1], p23 = d_[2] * d_[3];                   \
    float p45 = d_[4] * d_[5], p67 = d_[6] * d_[7];                   \
    float q03 = p01 * p23, q47 = p45 * p67;                           \
    float inv = __builtin_amdgcn_rcpf(q03 * q47);                     \
    float i03 = inv * q47, i47 = inv * q03;                           \
    float i01 = i03 * p23, i23 = i03 * p01;                           \
    float i45 = i47 * p67, i67 = i47 * p45;                           \
    float h0 = fminf(n_[0] * (i01 * d_[1]), 1.f);                     \
    float h1 = fminf(n_[1] * (i01 * d_[0]), 1.f);                     \
    float h2 = fminf(n_[2] * (i23 * d_[3]), 1.f);                     \
    float h3 = fminf(n_[3] * (i23 * d_[2]), 1.f);                     \
    float h4 = fminf(n_[4] * (i45 * d_[5]), 1.f);                     \
    float h5 = fminf(n_[5] * (i45 * d_[4]), 1.f);                     \
    float h6 = fminf(n_[6] * (i67 * d_[7]), 1.f);                     \
    float h7 = fminf(n_[7] * (i67 * d_[6]), 1.f);                     \
    float s0 = fmaf(h0, w2[0], h1 * w2[1]);                           \
    float s1 = fmaf(h2, w2[2], h3 * w2[3]);                           \
    float s2 = fmaf(h4, w2[4], h5 * w2[5]);                           \
    float s3 = fmaf(h6, w2[6], h7 * w2[7]);                           \
    float ps = (s0 + s1) + (s2 + s3);                                 \
    ps += dppf<0xB1>(ps); /* add partner lane's half */               \
    float z = state + bb2 + ps;                                       \
    z = (AB_ == 1) ? z : state;                                       \
    /* sigmoid(z) = 0.5 + 0.5*tanh(z/2), Pade[5/4], one rcp */        \
    float u_ = z * 0.5f;                                              \
    float uy = u_ * u_;                                               \
    float sn = u_ * fmaf(uy, uy + 105.f, 945.f);                      \
    float sd = fmaf(uy, fmaf(uy, 15.f, 420.f), 945.f);                \
    float th = sn * __builtin_amdgcn_rcpf(sd);                        \
    th = fminf(fmaxf(th, -1.f), 1.f);                                 \
    state = fmaf(0.5f, th, 0.5f);                                     \
  }

  float rA, rB, rC;
  int aA, aB, aC, pA, pB, pC;
  LOAD_RAW(0, rA, aA, pA);
  LOAD_RAW(1, rB, aB, pB);

  float tc0[8], tc1[8];
  GATHER(pA, tc0, tc1);  // group 0 tables (one-time stall)

  float state = 0.f;

  for (int g = 0; g < NG; ++g) {
    LOAD_RAW(g + 2, rC, aC, pC);  // raw streams: 2-group (4-step) lead
    float tn0[8], tn1[8];
    GATHER(pB, tn0, tn1);         // tables for group g+1: 1-group lead

    // broadcast this group's r/a within the pair (pure DPP)
    float r0 = dppf<0xA0>(rA), r1 = dppf<0xF5>(rA);
    int ab0 = dppi<0xA0>(aA), ab1 = dppi<0xF5>(aA);
    // fold r into table regs: pre[j] = r*wb[j] + emb_proj[j] (off dep path)
#pragma unroll
    for (int j = 0; j < 8; ++j) {
      tc0[j] = fmaf(r0, wb[j], tc0[j]);
      tc1[j] = fmaf(r1, wb[j], tc1[j]);
    }

    STEP(tc0, ab0);
    float sv = state;   // state after even step
    STEP(tc1, ab1);

    float outv = (sub == 0) ? sv : state;
    op[(size_t)(g * 2 + sub) * BA] = outv;

    // rotate pipeline
    rA = rB; aA = aB;
    rB = rC; aB = aC; pB = pC;
#pragma unroll
    for (int j = 0; j < 8; ++j) { tc0[j] = tn0[j]; tc1[j] = tn1[j]; }
  }
}

extern "C" void kernel_launch(void* const* d_in, const int* in_sizes, int n_in,
                              void* d_out, int out_size, void* d_ws, size_t ws_size,
                              hipStream_t stream) {
  const int* c_Action = (const int*)d_in[0];
  const float* c_Reward = (const float*)d_in[1];
  const int* c_ParticipantID = (const int*)d_in[2];
  const float* emb_table = (const float*)d_in[3];
  const float* W1 = (const float*)d_in[4];
  const float* b1 = (const float*)d_in[5];
  const float* W2 = (const float*)d_in[6];
  const float* b2 = (const float*)d_in[7];
  float* out = (float*)d_out;
  float* proj = (float*)d_ws;  // 16000 floats = 64 KB scratch

  emb_proj_kernel<<<(TABN + 255) / 256, 256, 0, stream>>>(emb_table, W1, b1, proj);

  // 32768 chains * 2 lanes = 65536 threads; 256 blocks of 256
  scan_kernel<<<(BA * 2) / 256, 256, 0, stream>>>(
      c_Action, c_Reward, c_ParticipantID, W1, W2, b2, proj, out);
}

// Round 9
// 182.894 us; speedup vs baseline: 1.1046x; 1.1046x over previous
//
#include <hip/hip_runtime.h>

#define S_DIM 512
#define B_DIM 16384
#define A_DIM 2
#define BA (B_DIM * A_DIM)   // 32768
#define HID 16
#define EMB 8
#define NPART 1000
#define TABN (NPART * HID)   // 16000
#define NG (S_DIM / 4)       // 128 groups of 4 steps

typedef __attribute__((ext_vector_type(2))) float f2;

// Kernel 1: emb_proj[p][j] = b1[j] + sum_k emb_table[p][k] * W1[2+k][j]
__global__ __launch_bounds__(256) void emb_proj_kernel(
    const float* __restrict__ emb_table, const float* __restrict__ W1,
    const float* __restrict__ b1, float* __restrict__ proj) {
  int idx = blockIdx.x * 256 + threadIdx.x;
  if (idx >= TABN) return;
  int p = idx >> 4;
  int j = idx & 15;
  float acc = b1[j];
#pragma unroll
  for (int k = 0; k < EMB; ++k)
    acc = fmaf(emb_table[p * EMB + k], W1[(2 + k) * HID + j], acc);
  proj[idx] = acc;
}

// Packed f32 (VOP3P): 2 FP32 ops per instruction -> halves VALU issue.
__device__ __forceinline__ f2 pkfma(f2 a, f2 b, f2 c) {
  f2 d;
  asm("v_pk_fma_f32 %0, %1, %2, %3" : "=v"(d) : "v"(a), "v"(b), "v"(c));
  return d;
}
__device__ __forceinline__ f2 pkmul(f2 a, f2 b) {
  f2 d;
  asm("v_pk_mul_f32 %0, %1, %2" : "=v"(d) : "v"(a), "v"(b));
  return d;
}
__device__ __forceinline__ f2 pkadd(f2 a, f2 b) {
  f2 d;
  asm("v_pk_add_f32 %0, %1, %2" : "=v"(d) : "v"(a), "v"(b));
  return d;
}
__device__ __forceinline__ f2 splat(float s) { f2 v; v.x = s; v.y = s; return v; }

// DPP quad-perm (pure VALU)
template <int CTRL>
__device__ __forceinline__ int dppi(int x) {
  return __builtin_amdgcn_update_dpp(0, x, CTRL, 0xF, 0xF, true);
}
template <int CTRL>
__device__ __forceinline__ float dppf(float x) {
  return __builtin_bit_cast(float, dppi<CTRL>(__builtin_bit_cast(int, x)));
}
#define BC(K) ((K) | ((K) << 2) | ((K) << 4) | ((K) << 6))  // bcast lane K of quad

// Scan: 4 lanes/chain (R5's best structure), 2 waves/SIMD. Packed Pade[5/4]
// tanh with ONE batched rcp per step (4 denominators), Pade sigmoid.
// Trans: 10 -> 2 per lane-step. Groups of 4 steps; raw 2-group lead,
// table gather 1-group lead. All cross-lane via DPP.
__global__ __launch_bounds__(256, 2) void scan_kernel(
    const int* __restrict__ act, const float* __restrict__ rew,
    const int* __restrict__ pid, const float* __restrict__ W1,
    const float* __restrict__ W2, const float* __restrict__ b2,
    const float* __restrict__ proj, float* __restrict__ out) {
  int t = blockIdx.x * 256 + threadIdx.x;  // 0 .. 131071
  int chain = t >> 2;                      // 0 .. 32767 (= b*A + a)
  int sub = t & 3;
  int b = chain >> 1;
  int j0 = sub << 2;

  float4 wav = *(const float4*)(W1 + j0);
  float4 wbv = *(const float4*)(W1 + HID + j0);
  float4 w2v = *(const float4*)(W2 + j0);
  f2 wa0 = {wav.x, wav.y}, wa1 = {wav.z, wav.w};
  f2 wb0 = {wbv.x, wbv.y}, wb1 = {wbv.z, wbv.w};
  f2 w20 = {w2v.x, w2v.y}, w21 = {w2v.z, w2v.w};
  float bb2 = b2[0];
  const f2 k105 = {105.f, 105.f}, k945 = {945.f, 945.f};
  const f2 k15 = {15.f, 15.f}, k420 = {420.f, 420.f};

  const float* rp = rew + chain;
  const int* ap = act + chain;
  const int* pp = pid + b;
  const float* tb = proj + j0;
  float* op = out + chain;

#define LOAD_RAW(G_, RD, AD, PD)              \
  {                                           \
    int gg_ = (G_) < NG ? (G_) : NG - 1;      \
    size_t st_ = (size_t)(gg_ * 4 + sub);     \
    RD = rp[st_ * BA];                        \
    AD = ap[st_ * BA];                        \
    PD = pp[st_ * B_DIM];                     \
  }

// bcast each step's pid within the quad, load this lane's 4 columns of it
#define GATHER(PS, T0, T1, T2, T3)            \
  {                                           \
    int pq0_ = dppi<BC(0)>(PS);               \
    int pq1_ = dppi<BC(1)>(PS);               \
    int pq2_ = dppi<BC(2)>(PS);               \
    int pq3_ = dppi<BC(3)>(PS);               \
    T0 = *(const float4*)(tb + pq0_ * HID);   \
    T1 = *(const float4*)(tb + pq1_ * HID);   \
    T2 = *(const float4*)(tb + pq2_ * HID);   \
    T3 = *(const float4*)(tb + pq3_ * HID);   \
  }

// One step. T_ = float4 table row (this lane's 4 units). R_/AF_ scalars.
// tanh(x) x>=0: Pade[5/4] x(945+105y+y^2)/(945+420y+15y^2), y=x^2; all 4
// denominators share one rcp via exclusion products. Clamp h to 1.
// All internals use reserved _q-suffixed names to avoid macro capture.
#define STEP(T_, R_, AF_, STO_)                                        \
  {                                                                    \
    f2 tA_q = {T_.x, T_.y}, tB_q = {T_.z, T_.w};                       \
    f2 rv_q = splat(R_), st_q = splat(state);                          \
    f2 x0_q = pkfma(st_q, wa0, pkfma(rv_q, wb0, tA_q));                \
    f2 x1_q = pkfma(st_q, wa1, pkfma(rv_q, wb1, tB_q));                \
    x0_q.x = fmaxf(x0_q.x, 0.f); x0_q.y = fmaxf(x0_q.y, 0.f);          \
    x1_q.x = fmaxf(x1_q.x, 0.f); x1_q.y = fmaxf(x1_q.y, 0.f);          \
    f2 y0_q = pkmul(x0_q, x0_q), y1_q = pkmul(x1_q, x1_q);             \
    f2 n0_q = pkmul(x0_q, pkfma(y0_q, pkadd(y0_q, k105), k945));       \
    f2 n1_q = pkmul(x1_q, pkfma(y1_q, pkadd(y1_q, k105), k945));       \
    f2 d0_q = pkfma(y0_q, pkfma(y0_q, k15, k420), k945);               \
    f2 d1_q = pkfma(y1_q, pkfma(y1_q, k15, k420), k945);               \
    f2 m_q = pkmul(d0_q, d1_q); /* {dA*dC, dB*dD} */                   \
    float inv_q = __builtin_amdgcn_rcpf(m_q.x * m_q.y);                \
    f2 e0_q = {m_q.y * d1_q.x, m_q.x * d1_q.y};                        \
    f2 e1_q = {m_q.y * d0_q.x, m_q.x * d0_q.y};                        \
    f2 iv_q = splat(inv_q);                                            \
    f2 h0_q = pkmul(n0_q, pkmul(e0_q, iv_q));                          \
    f2 h1_q = pkmul(n1_q, pkmul(e1_q, iv_q));                          \
    h0_q.x = fminf(h0_q.x, 1.f); h0_q.y = fminf(h0_q.y, 1.f);          \
    h1_q.x = fminf(h1_q.x, 1.f); h1_q.y = fminf(h1_q.y, 1.f);          \
    f2 ac_q = pkfma(h1_q, w21, pkmul(h0_q, w20));                      \
    float ps_q = ac_q.x + ac_q.y;                                      \
    ps_q += dppf<0xB1>(ps_q); /* xor1 */                               \
    ps_q += dppf<0x4E>(ps_q); /* xor2 */                               \
    float z_q = fmaf(AF_, ps_q + bb2, state); /* AF_ in {0.,1.} */     \
    /* sigmoid(z) = 0.5 + 0.5*tanh(z/2), Pade[5/4], one rcp */         \
    float u_q = z_q * 0.5f, uy_q = u_q * u_q;                          \
    float sn_q = u_q * fmaf(uy_q, uy_q + 105.f, 945.f);                \
    float sd_q = fmaf(uy_q, fmaf(uy_q, 15.f, 420.f), 945.f);           \
    float th_q = sn_q * __builtin_amdgcn_rcpf(sd_q);                   \
    th_q = fminf(fmaxf(th_q, -1.f), 1.f);                              \
    state = fmaf(0.5f, th_q, 0.5f);                                    \
    STO_ = state;                                                      \
  }

  float rA, rB, rC;
  int aA, aB, aC, pA, pB, pC;
  LOAD_RAW(0, rA, aA, pA);
  LOAD_RAW(1, rB, aB, pB);

  float4 t0, t1, t2, t3;
  GATHER(pA, t0, t1, t2, t3);  // group 0 (one-time stall)

  float state = 0.f;

  for (int g = 0; g < NG; ++g) {
    LOAD_RAW(g + 2, rC, aC, pC);       // raw: 2-group (8-step) lead
    float4 u0, u1, u2, u3;
    GATHER(pB, u0, u1, u2, u3);        // table: 1-group lead

    // broadcast this group's r and action-mask (as float) via DPP
    float r0 = dppf<BC(0)>(rA), r1 = dppf<BC(1)>(rA);
    float r2 = dppf<BC(2)>(rA), r3 = dppf<BC(3)>(rA);
    float afq = (float)aA;  // a in {0,1}
    float af0 = dppf<BC(0)>(afq), af1 = dppf<BC(1)>(afq);
    float af2 = dppf<BC(2)>(afq), af3 = dppf<BC(3)>(afq);

    float s0, s1, s2, s3;
    STEP(t0, r0, af0, s0);
    STEP(t1, r1, af1, s1);
    STEP(t2, r2, af2, s2);
    STEP(t3, r3, af3, s3);

    // batched store: lane sub writes step 4g+sub (cndmask cascade)
    float sv = (sub & 1) ? s1 : s0;
    float sw = (sub & 1) ? s3 : s2;
    sv = (sub & 2) ? sw : sv;
    op[(size_t)(g * 4 + sub) * BA] = sv;

    // rotate pipeline
    rA = rB; aA = aB;
    rB = rC; aB = aC; pB = pC;
    t0 = u0; t1 = u1; t2 = u2; t3 = u3;
  }
}

extern "C" void kernel_launch(void* const* d_in, const int* in_sizes, int n_in,
                              void* d_out, int out_size, void* d_ws, size_t ws_size,
                              hipStream_t stream) {
  const int* c_Action = (const int*)d_in[0];
  const float* c_Reward = (const float*)d_in[1];
  const int* c_ParticipantID = (const int*)d_in[2];
  const float* emb_table = (const float*)d_in[3];
  const float* W1 = (const float*)d_in[4];
  const float* b1 = (const float*)d_in[5];
  const float* W2 = (const float*)d_in[6];
  const float* b2 = (const float*)d_in[7];
  float* out = (float*)d_out;
  float* proj = (float*)d_ws;  // 16000 floats = 64 KB scratch

  emb_proj_kernel<<<(TABN + 255) / 256, 256, 0, stream>>>(emb_table, W1, b1, proj);

  // 32768 chains * 4 lanes = 131072 threads; 512 blocks of 256
  scan_kernel<<<(BA * 4) / 256, 256, 0, stream>>>(
      c_Action, c_Reward, c_ParticipantID, W1, W2, b2, proj, out);
}

// Round 10
// 177.492 us; speedup vs baseline: 1.1383x; 1.0304x over previous
//
#include <hip/hip_runtime.h>

#define S_DIM 512
#define B_DIM 16384
#define A_DIM 2
#define BA (B_DIM * A_DIM)   // 32768
#define HID 16
#define EMB 8
#define NPART 1000
#define TABN (NPART * HID)   // 16000
#define NG (S_DIM / 4)       // 128 groups of 4 steps

// Kernel 1: emb_proj[p][j] = b1[j] + sum_k emb_table[p][k] * W1[2+k][j]
__global__ __launch_bounds__(256) void emb_proj_kernel(
    const float* __restrict__ emb_table, const float* __restrict__ W1,
    const float* __restrict__ b1, float* __restrict__ proj) {
  int idx = blockIdx.x * 256 + threadIdx.x;
  if (idx >= TABN) return;
  int p = idx >> 4;
  int j = idx & 15;
  float acc = b1[j];
#pragma unroll
  for (int k = 0; k < EMB; ++k)
    acc = fmaf(emb_table[p * EMB + k], W1[(2 + k) * HID + j], acc);
  proj[idx] = acc;
}

// DPP quad-perm (pure VALU)
template <int CTRL>
__device__ __forceinline__ int dppi(int x) {
  return __builtin_amdgcn_update_dpp(0, x, CTRL, 0xF, 0xF, true);
}
template <int CTRL>
__device__ __forceinline__ float dppf(float x) {
  return __builtin_bit_cast(float, dppi<CTRL>(__builtin_bit_cast(int, x)));
}
#define BC(K) ((K) | ((K) << 2) | ((K) << 4) | ((K) << 6))  // bcast lane K of quad

// Scan: 4 lanes/chain (R5 structure, scalar math). Trans cut 10 -> 2 per
// lane-step: Pade[5/4] tanh, ONE rcp batched over the 4 units (short
// exclusion-product unwind), Pade sigmoid (1 rcp). No packed-f32 (gfx950
// has no fp32 dual-issue: v_pk_*_f32 is issue-neutral + mov bloat).
__global__ __launch_bounds__(256, 2) void scan_kernel(
    const int* __restrict__ act, const float* __restrict__ rew,
    const int* __restrict__ pid, const float* __restrict__ W1,
    const float* __restrict__ W2, const float* __restrict__ b2,
    const float* __restrict__ proj, float* __restrict__ out) {
  int t = blockIdx.x * 256 + threadIdx.x;  // 0 .. 131071
  int chain = t >> 2;                      // 0 .. 32767 (= b*A + a)
  int sub = t & 3;
  int b = chain >> 1;
  int j0 = sub << 2;

  float4 wav = *(const float4*)(W1 + j0);        // W1[0][j]
  float4 wbv = *(const float4*)(W1 + HID + j0);  // W1[1][j]
  float4 w2v = *(const float4*)(W2 + j0);        // W2[j][0]
  float bb2 = b2[0];

  const float* rp = rew + chain;
  const int* ap = act + chain;
  const int* pp = pid + b;
  const float* tb = proj + j0;
  float* op = out + chain;

#define LOAD_RAW(G_, RD, AD, PD)              \
  {                                           \
    int gg_ = (G_) < NG ? (G_) : NG - 1;      \
    size_t st_ = (size_t)(gg_ * 4 + sub);     \
    RD = rp[st_ * BA];                        \
    AD = ap[st_ * BA];                        \
    PD = pp[st_ * B_DIM];                     \
  }

#define GATHER(PS, T0, T1, T2, T3)            \
  {                                           \
    int pq0_ = dppi<BC(0)>(PS);               \
    int pq1_ = dppi<BC(1)>(PS);               \
    int pq2_ = dppi<BC(2)>(PS);               \
    int pq3_ = dppi<BC(3)>(PS);               \
    T0 = *(const float4*)(tb + pq0_ * HID);   \
    T1 = *(const float4*)(tb + pq1_ * HID);   \
    T2 = *(const float4*)(tb + pq2_ * HID);   \
    T3 = *(const float4*)(tb + pq3_ * HID);   \
  }

// One step, scalar. tanh(x), x in [0,4.6]: Pade[5/4]
// x(945+105y+y^2)/(945+420y+15y^2), y=x^2. One rcp for all 4 denominators.
#define STEP(T_, R_, AF_, STO_)                                         \
  {                                                                     \
    float x0_q = fmaf(state, wav.x, fmaf(R_, wbv.x, T_.x));             \
    float x1_q = fmaf(state, wav.y, fmaf(R_, wbv.y, T_.y));             \
    float x2_q = fmaf(state, wav.z, fmaf(R_, wbv.z, T_.z));             \
    float x3_q = fmaf(state, wav.w, fmaf(R_, wbv.w, T_.w));             \
    x0_q = fminf(fmaxf(x0_q, 0.f), 4.6f);                               \
    x1_q = fminf(fmaxf(x1_q, 0.f), 4.6f);                               \
    x2_q = fminf(fmaxf(x2_q, 0.f), 4.6f);                               \
    x3_q = fminf(fmaxf(x3_q, 0.f), 4.6f);                               \
    float y0_q = x0_q * x0_q, y1_q = x1_q * x1_q;                       \
    float y2_q = x2_q * x2_q, y3_q = x3_q * x3_q;                       \
    float n0_q = x0_q * fmaf(y0_q, y0_q + 105.f, 945.f);                \
    float n1_q = x1_q * fmaf(y1_q, y1_q + 105.f, 945.f);                \
    float n2_q = x2_q * fmaf(y2_q, y2_q + 105.f, 945.f);                \
    float n3_q = x3_q * fmaf(y3_q, y3_q + 105.f, 945.f);                \
    float d0_q = fmaf(y0_q, fmaf(y0_q, 15.f, 420.f), 945.f);            \
    float d1_q = fmaf(y1_q, fmaf(y1_q, 15.f, 420.f), 945.f);            \
    float d2_q = fmaf(y2_q, fmaf(y2_q, 15.f, 420.f), 945.f);            \
    float d3_q = fmaf(y3_q, fmaf(y3_q, 15.f, 420.f), 945.f);            \
    float p01_q = d0_q * d1_q, p23_q = d2_q * d3_q;                     \
    float inv_q = __builtin_amdgcn_rcpf(p01_q * p23_q);                 \
    float i01_q = inv_q * p23_q, i23_q = inv_q * p01_q;                 \
    float h0_q = fminf(n0_q * (i01_q * d1_q), 1.f);                     \
    float h1_q = fminf(n1_q * (i01_q * d0_q), 1.f);                     \
    float h2_q = fminf(n2_q * (i23_q * d3_q), 1.f);                     \
    float h3_q = fminf(n3_q * (i23_q * d2_q), 1.f);                     \
    float s0_q = fmaf(h0_q, w2v.x, h1_q * w2v.y);                       \
    float s1_q = fmaf(h2_q, w2v.z, h3_q * w2v.w);                       \
    float ps_q = s0_q + s1_q;                                           \
    ps_q += dppf<0xB1>(ps_q); /* xor1 */                                \
    ps_q += dppf<0x4E>(ps_q); /* xor2 */                                \
    float z_q = fmaf(AF_, ps_q + bb2, state); /* AF_ in {0.,1.} */      \
    /* sigmoid(z)=0.5+0.5*tanh(z/2), Pade[5/4], 1 rcp */                \
    float u_q = z_q * 0.5f, uy_q = u_q * u_q;                           \
    float sn_q = u_q * fmaf(uy_q, uy_q + 105.f, 945.f);                 \
    float sd_q = fmaf(uy_q, fmaf(uy_q, 15.f, 420.f), 945.f);            \
    float th_q = sn_q * __builtin_amdgcn_rcpf(sd_q);                    \
    th_q = fminf(fmaxf(th_q, -1.f), 1.f);                               \
    state = fmaf(0.5f, th_q, 0.5f);                                     \
    STO_ = state;                                                       \
  }

  float rA, rB, rC;
  int aA, aB, aC, pA, pB, pC;
  LOAD_RAW(0, rA, aA, pA);
  LOAD_RAW(1, rB, aB, pB);

  float4 t0, t1, t2, t3;
  GATHER(pA, t0, t1, t2, t3);  // group 0 (one-time stall)

  float state = 0.f;

  for (int g = 0; g < NG; ++g) {
    LOAD_RAW(g + 2, rC, aC, pC);       // raw: 2-group (8-step) lead
    float4 u0, u1, u2, u3;
    GATHER(pB, u0, u1, u2, u3);        // table: 1-group lead

    // broadcast this group's r and action-mask (as float) via DPP
    float r0 = dppf<BC(0)>(rA), r1 = dppf<BC(1)>(rA);
    float r2 = dppf<BC(2)>(rA), r3 = dppf<BC(3)>(rA);
    float afq = (float)aA;  // a in {0,1}
    float af0 = dppf<BC(0)>(afq), af1 = dppf<BC(1)>(afq);
    float af2 = dppf<BC(2)>(afq), af3 = dppf<BC(3)>(afq);

    float s0, s1, s2, s3;
    STEP(t0, r0, af0, s0);
    STEP(t1, r1, af1, s1);
    STEP(t2, r2, af2, s2);
    STEP(t3, r3, af3, s3);

    // batched store: lane sub writes step 4g+sub
    float sv = (sub & 1) ? s1 : s0;
    float sw = (sub & 1) ? s3 : s2;
    sv = (sub & 2) ? sw : sv;
    op[(size_t)(g * 4 + sub) * BA] = sv;

    // rotate pipeline
    rA = rB; aA = aB;
    rB = rC; aB = aC; pB = pC;
    t0 = u0; t1 = u1; t2 = u2; t3 = u3;
  }
}

extern "C" void kernel_launch(void* const* d_in, const int* in_sizes, int n_in,
                              void* d_out, int out_size, void* d_ws, size_t ws_size,
                              hipStream_t stream) {
  const int* c_Action = (const int*)d_in[0];
  const float* c_Reward = (const float*)d_in[1];
  const int* c_ParticipantID = (const int*)d_in[2];
  const float* emb_table = (const float*)d_in[3];
  const float* W1 = (const float*)d_in[4];
  const float* b1 = (const float*)d_in[5];
  const float* W2 = (const float*)d_in[6];
  const float* b2 = (const float*)d_in[7];
  float* out = (float*)d_out;
  float* proj = (float*)d_ws;  // 16000 floats = 64 KB scratch

  emb_proj_kernel<<<(TABN + 255) / 256, 256, 0, stream>>>(emb_table, W1, b1, proj);

  // 32768 chains * 4 lanes = 131072 threads; 512 blocks of 256
  scan_kernel<<<(BA * 4) / 256, 256, 0, stream>>>(
      c_Action, c_Reward, c_ParticipantID, W1, W2, b2, proj, out);
}

// Round 11
// 171.377 us; speedup vs baseline: 1.1789x; 1.0357x over previous
//
#include <hip/hip_runtime.h>

#define S_DIM 512
#define B_DIM 16384
#define A_DIM 2
#define BA (B_DIM * A_DIM)   // 32768
#define HID 16
#define EMB 8
#define NPART 1000
#define TABN (NPART * HID)   // 16000
#define NG (S_DIM / 4)       // 128 groups of 4 steps
#define HALFC 16384          // chain-set split: thread handles c and c+16384

// Kernel 1: emb_proj[p][j] = b1[j] + sum_k emb_table[p][k] * W1[2+k][j]
__global__ __launch_bounds__(256) void emb_proj_kernel(
    const float* __restrict__ emb_table, const float* __restrict__ W1,
    const float* __restrict__ b1, float* __restrict__ proj) {
  int idx = blockIdx.x * 256 + threadIdx.x;
  if (idx >= TABN) return;
  int p = idx >> 4;
  int j = idx & 15;
  float acc = b1[j];
#pragma unroll
  for (int k = 0; k < EMB; ++k)
    acc = fmaf(emb_table[p * EMB + k], W1[(2 + k) * HID + j], acc);
  proj[idx] = acc;
}

// DPP quad-perm (pure VALU)
template <int CTRL>
__device__ __forceinline__ int dppi(int x) {
  return __builtin_amdgcn_update_dpp(0, x, CTRL, 0xF, 0xF, true);
}
template <int CTRL>
__device__ __forceinline__ float dppf(float x) {
  return __builtin_bit_cast(float, dppi<CTRL>(__builtin_bit_cast(int, x)));
}
#define BC(K) ((K) | ((K) << 2) | ((K) << 4) | ((K) << 6))  // bcast lane K of quad

// Scan: R5's measured-best per-step math (exp2+rcp tanh), L=4 lanes/chain,
// but TWO independent chains per thread (c and c+16384). 65536 threads =
// 1 wave/SIMD; the two recurrences interleave in one instruction stream,
// so chain B's unit math fills chain A's serial sigmoid-tail stalls.
// Total issue/SIMD unchanged; stall (40% at R5) is the target.
__global__ __launch_bounds__(256, 1) void scan_kernel(
    const int* __restrict__ act, const float* __restrict__ rew,
    const int* __restrict__ pid, const float* __restrict__ W1,
    const float* __restrict__ W2, const float* __restrict__ b2,
    const float* __restrict__ proj, float* __restrict__ out) {
  int t = blockIdx.x * 256 + threadIdx.x;  // 0 .. 65535
  int chain0 = t >> 2;                     // 0 .. 16383
  int chain1 = chain0 + HALFC;             // 16384 .. 32767
  int sub = t & 3;
  int j0 = sub << 2;

  float4 wav = *(const float4*)(W1 + j0);        // W1[0][j]
  float4 wbv = *(const float4*)(W1 + HID + j0);  // W1[1][j]
  float4 w2v = *(const float4*)(W2 + j0);        // W2[j][0]
  float bb2 = b2[0];

  const float* rp0 = rew + chain0;
  const int* ap0 = act + chain0;
  const int* pp0 = pid + (chain0 >> 1);
  const float* rp1 = rew + chain1;
  const int* ap1 = act + chain1;
  const int* pp1 = pid + (chain1 >> 1);
  const float* tbl = proj + j0;
  float* op0 = out + chain0;
  float* op1 = out + chain1;

#define LOAD_RAW(G_, RP_, AP_, PP_, RD, AD, PD)  \
  {                                              \
    int gg_ = (G_) < NG ? (G_) : NG - 1;         \
    size_t st_ = (size_t)(gg_ * 4 + sub);        \
    RD = RP_[st_ * BA];                          \
    AD = AP_[st_ * BA];                          \
    PD = PP_[st_ * B_DIM];                       \
  }

#define GATHER(PS, T0, T1, T2, T3)              \
  {                                             \
    int pq0_ = dppi<BC(0)>(PS);                 \
    int pq1_ = dppi<BC(1)>(PS);                 \
    int pq2_ = dppi<BC(2)>(PS);                 \
    int pq3_ = dppi<BC(3)>(PS);                 \
    T0 = *(const float4*)(tbl + pq0_ * HID);    \
    T1 = *(const float4*)(tbl + pq1_ * HID);    \
    T2 = *(const float4*)(tbl + pq2_ * HID);    \
    T3 = *(const float4*)(tbl + pq3_ * HID);    \
  }

// R5's exact step math. STATE_ is the per-set state variable.
#define STEP(STATE_, T_, R_, AF_, STO_)                                 \
  {                                                                     \
    float x0_k = fmaf(STATE_, wav.x, fmaf(R_, wbv.x, T_.x));            \
    float x1_k = fmaf(STATE_, wav.y, fmaf(R_, wbv.y, T_.y));            \
    float x2_k = fmaf(STATE_, wav.z, fmaf(R_, wbv.z, T_.z));            \
    float x3_k = fmaf(STATE_, wav.w, fmaf(R_, wbv.w, T_.w));            \
    x0_k = fmaxf(x0_k, 0.f);                                            \
    x1_k = fmaxf(x1_k, 0.f);                                            \
    x2_k = fmaxf(x2_k, 0.f);                                            \
    x3_k = fmaxf(x3_k, 0.f);                                            \
    float e0_k = __builtin_amdgcn_exp2f(x0_k * 2.8853900817779268f);    \
    float e1_k = __builtin_amdgcn_exp2f(x1_k * 2.8853900817779268f);    \
    float e2_k = __builtin_amdgcn_exp2f(x2_k * 2.8853900817779268f);    \
    float e3_k = __builtin_amdgcn_exp2f(x3_k * 2.8853900817779268f);    \
    float h0_k = fmaf(-2.f, __builtin_amdgcn_rcpf(e0_k + 1.f), 1.f);    \
    float h1_k = fmaf(-2.f, __builtin_amdgcn_rcpf(e1_k + 1.f), 1.f);    \
    float h2_k = fmaf(-2.f, __builtin_amdgcn_rcpf(e2_k + 1.f), 1.f);    \
    float h3_k = fmaf(-2.f, __builtin_amdgcn_rcpf(e3_k + 1.f), 1.f);    \
    float s0_k = fmaf(h0_k, w2v.x, h1_k * w2v.y);                       \
    float s1_k = fmaf(h2_k, w2v.z, h3_k * w2v.w);                       \
    float ps_k = s0_k + s1_k;                                           \
    ps_k += dppf<0xB1>(ps_k); /* xor1 */                                \
    ps_k += dppf<0x4E>(ps_k); /* xor2 */                                \
    float z_k = fmaf(AF_, ps_k + bb2, STATE_); /* AF_ in {0.,1.} */     \
    STATE_ = __builtin_amdgcn_rcpf(                                     \
        1.f + __builtin_amdgcn_exp2f(z_k * -1.4426950408889634f));      \
    STO_ = STATE_;                                                      \
  }

  float rA0, rB0, rC0, rA1, rB1, rC1;
  int aA0, aB0, aC0, pA0, pB0, pC0;
  int aA1, aB1, aC1, pA1, pB1, pC1;
  LOAD_RAW(0, rp0, ap0, pp0, rA0, aA0, pA0);
  LOAD_RAW(1, rp0, ap0, pp0, rB0, aB0, pB0);
  LOAD_RAW(0, rp1, ap1, pp1, rA1, aA1, pA1);
  LOAD_RAW(1, rp1, ap1, pp1, rB1, aB1, pB1);

  float4 ta0, ta1, ta2, ta3;  // set0 current tables
  float4 tc0, tc1, tc2, tc3;  // set1 current tables
  GATHER(pA0, ta0, ta1, ta2, ta3);
  GATHER(pA1, tc0, tc1, tc2, tc3);

  float state0 = 0.f, state1 = 0.f;

  for (int g = 0; g < NG; ++g) {
    LOAD_RAW(g + 2, rp0, ap0, pp0, rC0, aC0, pC0);  // 2-group lead
    LOAD_RAW(g + 2, rp1, ap1, pp1, rC1, aC1, pC1);
    float4 ua0, ua1, ua2, ua3, uc0, uc1, uc2, uc3;
    GATHER(pB0, ua0, ua1, ua2, ua3);                // 1-group lead
    GATHER(pB1, uc0, uc1, uc2, uc3);

    // broadcast this group's r and action-mask within each quad (DPP)
    float r0_0 = dppf<BC(0)>(rA0), r1_0 = dppf<BC(1)>(rA0);
    float r2_0 = dppf<BC(2)>(rA0), r3_0 = dppf<BC(3)>(rA0);
    float r0_1 = dppf<BC(0)>(rA1), r1_1 = dppf<BC(1)>(rA1);
    float r2_1 = dppf<BC(2)>(rA1), r3_1 = dppf<BC(3)>(rA1);
    float afx0 = (float)aA0, afx1 = (float)aA1;
    float af0_0 = dppf<BC(0)>(afx0), af1_0 = dppf<BC(1)>(afx0);
    float af2_0 = dppf<BC(2)>(afx0), af3_0 = dppf<BC(3)>(afx0);
    float af0_1 = dppf<BC(0)>(afx1), af1_1 = dppf<BC(1)>(afx1);
    float af2_1 = dppf<BC(2)>(afx1), af3_1 = dppf<BC(3)>(afx1);

    float o0_0, o1_0, o2_0, o3_0, o0_1, o1_1, o2_1, o3_1;
    // interleave the two independent recurrences step by step
    STEP(state0, ta0, r0_0, af0_0, o0_0);
    STEP(state1, tc0, r0_1, af0_1, o0_1);
    STEP(state0, ta1, r1_0, af1_0, o1_0);
    STEP(state1, tc1, r1_1, af1_1, o1_1);
    STEP(state0, ta2, r2_0, af2_0, o2_0);
    STEP(state1, tc2, r2_1, af2_1, o2_1);
    STEP(state0, ta3, r3_0, af3_0, o3_0);
    STEP(state1, tc3, r3_1, af3_1, o3_1);

    // batched store: lane sub writes step 4g+sub for each chain set
    float sv0 = (sub & 1) ? o1_0 : o0_0;
    float sw0 = (sub & 1) ? o3_0 : o2_0;
    sv0 = (sub & 2) ? sw0 : sv0;
    op0[(size_t)(g * 4 + sub) * BA] = sv0;
    float sv1 = (sub & 1) ? o1_1 : o0_1;
    float sw1 = (sub & 1) ? o3_1 : o2_1;
    sv1 = (sub & 2) ? sw1 : sv1;
    op1[(size_t)(g * 4 + sub) * BA] = sv1;

    // rotate pipelines
    rA0 = rB0; aA0 = aB0;
    rB0 = rC0; aB0 = aC0; pB0 = pC0;
    rA1 = rB1; aA1 = aB1;
    rB1 = rC1; aB1 = aC1; pB1 = pC1;
    ta0 = ua0; ta1 = ua1; ta2 = ua2; ta3 = ua3;
    tc0 = uc0; tc1 = uc1; tc2 = uc2; tc3 = uc3;
  }
}

extern "C" void kernel_launch(void* const* d_in, const int* in_sizes, int n_in,
                              void* d_out, int out_size, void* d_ws, size_t ws_size,
                              hipStream_t stream) {
  const int* c_Action = (const int*)d_in[0];
  const float* c_Reward = (const float*)d_in[1];
  const int* c_ParticipantID = (const int*)d_in[2];
  const float* emb_table = (const float*)d_in[3];
  const float* W1 = (const float*)d_in[4];
  const float* b1 = (const float*)d_in[5];
  const float* W2 = (const float*)d_in[6];
  const float* b2 = (const float*)d_in[7];
  float* out = (float*)d_out;
  float* proj = (float*)d_ws;  // 16000 floats = 64 KB scratch

  emb_proj_kernel<<<(TABN + 255) / 256, 256, 0, stream>>>(emb_table, W1, b1, proj);

  // 16384 chain-pairs * 4 lanes = 65536 threads; 256 blocks -> 1 wave/SIMD,
  // 2 interleaved chains per thread
  scan_kernel<<<(HALFC * 4) / 256, 256, 0, stream>>>(
      c_Action, c_Reward, c_ParticipantID, W1, W2, b2, proj, out);
}

// Round 12
// 120.615 us; speedup vs baseline: 1.6750x; 1.4209x over previous
//
#include <hip/hip_runtime.h>

#define S_DIM 512
#define B_DIM 16384
#define A_DIM 2
#define BA (B_DIM * A_DIM)   // 32768
#define HID 16
#define EMB 8
#define NPART 1000
#define TABN (NPART * HID)   // 16000
#define NG (S_DIM / 4)       // 128 groups of 4 steps
#define SCALE 2.8853900817779268f  // 2*log2(e): folded into proj/wa/wb

// Kernel 1: proj[p][j] = SCALE * (b1[j] + sum_k emb_table[p][k] * W1[2+k][j])
__global__ __launch_bounds__(256) void emb_proj_kernel(
    const float* __restrict__ emb_table, const float* __restrict__ W1,
    const float* __restrict__ b1, float* __restrict__ proj) {
  int idx = blockIdx.x * 256 + threadIdx.x;
  if (idx >= TABN) return;
  int p = idx >> 4;
  int j = idx & 15;
  float acc = b1[j];
#pragma unroll
  for (int k = 0; k < EMB; ++k)
    acc = fmaf(emb_table[p * EMB + k], W1[(2 + k) * HID + j], acc);
  proj[idx] = acc * SCALE;
}

// DPP quad-perm (pure VALU)
template <int CTRL>
__device__ __forceinline__ int dppi(int x) {
  return __builtin_amdgcn_update_dpp(0, x, CTRL, 0xF, 0xF, true);
}
template <int CTRL>
__device__ __forceinline__ float dppf(float x) {
  return __builtin_bit_cast(float, dppi<CTRL>(__builtin_bit_cast(int, x)));
}
#define BC(K) ((K) | ((K) << 2) | ((K) << 4) | ((K) << 6))  // bcast lane K of quad

// Scan: R5 structure (L=4, 2 waves/SIMD, group-4 batched loads, DPP-only),
// consolidated: 2*log2e prescale folded into proj/wa/wb (kills per-unit mul),
// state-independent pre = r*wb + T hoisted to group top (fill ILP for the
// serial step tails), unroll-2 (rotation movs renamed away).
__global__ __launch_bounds__(256, 2) void scan_kernel(
    const int* __restrict__ act, const float* __restrict__ rew,
    const int* __restrict__ pid, const float* __restrict__ W1,
    const float* __restrict__ W2, const float* __restrict__ b2,
    const float* __restrict__ proj, float* __restrict__ out) {
  int t = blockIdx.x * 256 + threadIdx.x;  // 0 .. 131071
  int chain = t >> 2;                      // 0 .. 32767 (= b*A + a)
  int sub = t & 3;
  int b = chain >> 1;
  int j0 = sub << 2;

  float4 wav = *(const float4*)(W1 + j0);        // W1[0][j], scaled below
  float4 wbv = *(const float4*)(W1 + HID + j0);  // W1[1][j], scaled below
  float4 w2v = *(const float4*)(W2 + j0);        // W2[j][0] (NOT scaled)
  wav.x *= SCALE; wav.y *= SCALE; wav.z *= SCALE; wav.w *= SCALE;
  wbv.x *= SCALE; wbv.y *= SCALE; wbv.z *= SCALE; wbv.w *= SCALE;
  float bb2 = b2[0];

  const float* rp = rew + chain;
  const int* ap = act + chain;
  const int* pp = pid + b;
  const float* tbl = proj + j0;
  float* op = out + chain;

#define LOAD_RAW(G_, RD, AD, PD)              \
  {                                           \
    int gg_ = (G_) < NG ? (G_) : NG - 1;      \
    size_t st_ = (size_t)(gg_ * 4 + sub);     \
    RD = rp[st_ * BA];                        \
    AD = ap[st_ * BA];                        \
    PD = pp[st_ * B_DIM];                     \
  }

#define GATHER(PS, T0, T1, T2, T3)            \
  {                                           \
    int pq0_ = dppi<BC(0)>(PS);               \
    int pq1_ = dppi<BC(1)>(PS);               \
    int pq2_ = dppi<BC(2)>(PS);               \
    int pq3_ = dppi<BC(3)>(PS);               \
    T0 = *(const float4*)(tbl + pq0_ * HID);  \
    T1 = *(const float4*)(tbl + pq1_ * HID);  \
    T2 = *(const float4*)(tbl + pq2_ * HID);  \
    T3 = *(const float4*)(tbl + pq3_ * HID);  \
  }

// One step. P_ = prefolded scaled input (r*wb' + T'), state-independent.
// arg = state*wa' + P_ is already 2x*log2e -> exp2 directly (no mul).
#define STEP(P_, AF_, STO_)                                             \
  {                                                                     \
    float x0_k = fmaf(state, wav.x, P_.x);                              \
    float x1_k = fmaf(state, wav.y, P_.y);                              \
    float x2_k = fmaf(state, wav.z, P_.z);                              \
    float x3_k = fmaf(state, wav.w, P_.w);                              \
    x0_k = fmaxf(x0_k, 0.f);                                            \
    x1_k = fmaxf(x1_k, 0.f);                                            \
    x2_k = fmaxf(x2_k, 0.f);                                            \
    x3_k = fmaxf(x3_k, 0.f);                                            \
    float e0_k = __builtin_amdgcn_exp2f(x0_k);                          \
    float e1_k = __builtin_amdgcn_exp2f(x1_k);                          \
    float e2_k = __builtin_amdgcn_exp2f(x2_k);                          \
    float e3_k = __builtin_amdgcn_exp2f(x3_k);                          \
    float h0_k = fmaf(-2.f, __builtin_amdgcn_rcpf(e0_k + 1.f), 1.f);    \
    float h1_k = fmaf(-2.f, __builtin_amdgcn_rcpf(e1_k + 1.f), 1.f);    \
    float h2_k = fmaf(-2.f, __builtin_amdgcn_rcpf(e2_k + 1.f), 1.f);    \
    float h3_k = fmaf(-2.f, __builtin_amdgcn_rcpf(e3_k + 1.f), 1.f);    \
    float s0_k = fmaf(h0_k, w2v.x, h1_k * w2v.y);                       \
    float s1_k = fmaf(h2_k, w2v.z, h3_k * w2v.w);                       \
    float ps_k = s0_k + s1_k;                                           \
    ps_k += dppf<0xB1>(ps_k); /* xor1 */                                \
    ps_k += dppf<0x4E>(ps_k); /* xor2 */                                \
    float z_k = fmaf(AF_, ps_k + bb2, state); /* AF_ in {0.,1.} */      \
    state = __builtin_amdgcn_rcpf(                                      \
        1.f + __builtin_amdgcn_exp2f(z_k * -1.4426950408889634f));      \
    STO_ = state;                                                       \
  }

  float rA, rB, rC;
  int aA, aB, aC, pA, pB, pC;
  LOAD_RAW(0, rA, aA, pA);
  LOAD_RAW(1, rB, aB, pB);

  float4 t0, t1, t2, t3;
  GATHER(pA, t0, t1, t2, t3);  // group 0 (one-time stall)

  float state = 0.f;

#pragma unroll 2
  for (int g = 0; g < NG; ++g) {
    LOAD_RAW(g + 2, rC, aC, pC);       // raw: 2-group (8-step) lead
    float4 u0, u1, u2, u3;
    GATHER(pB, u0, u1, u2, u3);        // table: 1-group lead

    // broadcast this group's r and action-mask (as float) via DPP
    float r0 = dppf<BC(0)>(rA), r1 = dppf<BC(1)>(rA);
    float r2 = dppf<BC(2)>(rA), r3 = dppf<BC(3)>(rA);
    float afq = (float)aA;  // a in {0,1}
    float af0 = dppf<BC(0)>(afq), af1 = dppf<BC(1)>(afq);
    float af2 = dppf<BC(2)>(afq), af3 = dppf<BC(3)>(afq);

    // hoisted state-independent pre-adds: 16 fmas of fill-ILP for the tails
    float4 p0, p1, p2, p3;
    p0.x = fmaf(r0, wbv.x, t0.x); p0.y = fmaf(r0, wbv.y, t0.y);
    p0.z = fmaf(r0, wbv.z, t0.z); p0.w = fmaf(r0, wbv.w, t0.w);
    p1.x = fmaf(r1, wbv.x, t1.x); p1.y = fmaf(r1, wbv.y, t1.y);
    p1.z = fmaf(r1, wbv.z, t1.z); p1.w = fmaf(r1, wbv.w, t1.w);
    p2.x = fmaf(r2, wbv.x, t2.x); p2.y = fmaf(r2, wbv.y, t2.y);
    p2.z = fmaf(r2, wbv.z, t2.z); p2.w = fmaf(r2, wbv.w, t2.w);
    p3.x = fmaf(r3, wbv.x, t3.x); p3.y = fmaf(r3, wbv.y, t3.y);
    p3.z = fmaf(r3, wbv.z, t3.z); p3.w = fmaf(r3, wbv.w, t3.w);

    float s0, s1, s2, s3;
    STEP(p0, af0, s0);
    STEP(p1, af1, s1);
    STEP(p2, af2, s2);
    STEP(p3, af3, s3);

    // batched store: lane sub writes step 4g+sub
    float sv = (sub & 1) ? s1 : s0;
    float sw = (sub & 1) ? s3 : s2;
    sv = (sub & 2) ? sw : sv;
    op[(size_t)(g * 4 + sub) * BA] = sv;

    // rotate pipeline (renamed away under unroll-2)
    rA = rB; aA = aB;
    rB = rC; aB = aC; pB = pC;
    t0 = u0; t1 = u1; t2 = u2; t3 = u3;
  }
}

extern "C" void kernel_launch(void* const* d_in, const int* in_sizes, int n_in,
                              void* d_out, int out_size, void* d_ws, size_t ws_size,
                              hipStream_t stream) {
  const int* c_Action = (const int*)d_in[0];
  const float* c_Reward = (const float*)d_in[1];
  const int* c_ParticipantID = (const int*)d_in[2];
  const float* emb_table = (const float*)d_in[3];
  const float* W1 = (const float*)d_in[4];
  const float* b1 = (const float*)d_in[5];
  const float* W2 = (const float*)d_in[6];
  const float* b2 = (const float*)d_in[7];
  float* out = (float*)d_out;
  float* proj = (float*)d_ws;  // 16000 floats = 64 KB scratch

  emb_proj_kernel<<<(TABN + 255) / 256, 256, 0, stream>>>(emb_table, W1, b1, proj);

  // 32768 chains * 4 lanes = 131072 threads; 512 blocks of 256
  scan_kernel<<<(BA * 4) / 256, 256, 0, stream>>>(
      c_Action, c_Reward, c_ParticipantID, W1, W2, b2, proj, out);
}